// Round 11
// baseline (855.277 us; speedup 1.0000x reference)
//
#include <hip/hip_runtime.h>
#include <hip/hip_bf16.h>

// ---------------------------------------------------------------------------
// CNN + EB dropout. r11:
//  - convs: NEW convmfma6: A double-buffered via global_load_lds, B staged
//    through REGISTERS into a single LDS buffer (ds_write at iteration top),
//    raw s_barrier + manual waitcnt (mid barrier does not drain A-prefetch),
//    48KB LDS (conv2) / 32KB (conv3) -> 3 blocks/CU; setprio around MFMA.
//    Buffer windows: Bt written only in [bar7(i-1),bar3(i)], read only in
//    [bar3(i),bar7(i)]; At[cur^1] gld_lds lands before bar7(i)'s vmcnt(0),
//    read from bar3(i+1). Data placement bit-identical to r10.
//  - fc1: converted to 6-product 3-term-split MFMA GEMM (same as dual/t/h6).
// ---------------------------------------------------------------------------

typedef __attribute__((ext_vector_type(8))) short bf16x8;
typedef __attribute__((ext_vector_type(4))) float f32x4;

__device__ __forceinline__ void split_bf16(float x, ushort& h, ushort& l) {
    __hip_bfloat16 bh = __float2bfloat16(x);
    float fh = __bfloat162float(bh);
    __hip_bfloat16 bl = __float2bfloat16(x - fh);
    h = *(ushort*)&bh;
    l = *(ushort*)&bl;
}

__device__ __forceinline__ void split3_bf16(float x, ushort& a, ushort& b,
                                            ushort& c) {
    __hip_bfloat16 ba = __float2bfloat16(x);
    float fa = __bfloat162float(ba);
    float r = x - fa;
    __hip_bfloat16 bb = __float2bfloat16(r);
    float fb = __bfloat162float(bb);
    __hip_bfloat16 bc = __float2bfloat16(r - fb);
    a = *(ushort*)&ba;
    b = *(ushort*)&bb;
    c = *(ushort*)&bc;
}

__device__ __forceinline__ void gld_lds16(const void* g, void* l) {
    __builtin_amdgcn_global_load_lds(
        (const __attribute__((address_space(1))) unsigned int*)g,
        (__attribute__((address_space(3))) unsigned int*)l, 16, 0, 0);
}

// ---------------- zero fill ----------------
__global__ void zero_k(float4* __restrict__ p, int n4) {
    int idx = blockIdx.x * 256 + threadIdx.x;
    int stride = gridDim.x * 256;
    float4 z = {0.f, 0.f, 0.f, 0.f};
    for (int i = idx; i < n4; i += stride) p[i] = z;
}

// ---------------- conv1 weight transpose ----------------
__global__ void transw_k(const float* __restrict__ in, float* __restrict__ out,
                         int OC, int K) {
    int idx = blockIdx.x * 256 + threadIdx.x;
    if (idx >= OC * K) return;
    int oc = idx / K, k = idx % K;
    out[k * OC + oc] = in[idx];
}

// ---------------- conv weight split: OIHW -> bf16 hi/lo [oc][tap*IC+ic] -----
__global__ void splitw_k(const float* __restrict__ in, ushort* __restrict__ hi,
                         ushort* __restrict__ lo, int OC, int IC) {
    int idx = blockIdx.x * 256 + threadIdx.x;
    if (idx >= OC * IC * 25) return;
    int oc = idx / (IC * 25);
    int r = idx % (IC * 25);
    int ic = r / 25, tap = r % 25;
    float v = in[idx];
    ushort h, l;
    split_bf16(v, h, l);
    size_t k = (size_t)oc * IC * 25 + tap * IC + ic;
    hi[k] = h;
    lo[k] = l;
}

// ---------------- raw 3-term split (same [out][in] layout) ------------------
__global__ void splitw3_k(const float* __restrict__ in, ushort* __restrict__ out,
                          int off, int total) {
    int idx = blockIdx.x * 256 + threadIdx.x;
    if (idx >= total) return;
    ushort a, b, c;
    split3_bf16(in[idx], a, b, c);
    out[idx] = a;
    out[idx + off] = b;
    out[idx + 2 * off] = c;
}

// ---------------- fc2 relu + transpose 3-term split -------------------------
__global__ __launch_bounds__(256) void splitw3t_relu_k(
        const float* __restrict__ in, ushort* __restrict__ out, int off) {
    __shared__ float tile[64][65];
    const int bx = blockIdx.x & 31, by = blockIdx.x >> 5;
    const int j = threadIdx.x & 63, i0 = threadIdx.x >> 6;
    for (int i = i0; i < 64; i += 4)
        tile[i][j] = in[(size_t)(by * 64 + i) * 2048 + bx * 64 + j];
    __syncthreads();
    for (int r = i0; r < 64; r += 4) {
        float x = fmaxf(tile[j][r], 0.f);
        ushort a, b, c;
        split3_bf16(x, a, b, c);
        size_t o = (size_t)(bx * 64 + r) * 2048 + by * 64 + j;
        out[o] = a;
        out[o + off] = b;
        out[o + 2 * off] = c;
    }
}

// ---------------- conv1: f32 VALU, fused pool, writes pre-split hi/lo -------
__global__ __launch_bounds__(256) void conv1_v3(
        const float* __restrict__ x, const float* __restrict__ w1t,
        const float* __restrict__ b1, ushort* __restrict__ h1hi,
        ushort* __restrict__ h1lo) {
    __shared__ float simg[3 * 34 * 34];
    __shared__ float c1s[8][904];
    const int b = blockIdx.x, oc0 = blockIdx.y * 8, t = threadIdx.x;

    for (int i = t; i < 3 * 34 * 34; i += 256) simg[i] = 0.f;
    __syncthreads();
    for (int i = t; i < 3072; i += 256) {
        int ic = i >> 10, r = (i >> 5) & 31, c = i & 31;
        simg[ic * 1156 + (r + 1) * 34 + (c + 1)] = x[(size_t)b * 3072 + i];
    }
    __syncthreads();

    int base[4];
    bool valid[4];
#pragma unroll
    for (int j = 0; j < 4; j++) {
        int p = t + j * 256;
        valid[j] = p < 900;
        int oh = p / 30, ow = p % 30;
        base[j] = valid[j] ? oh * 34 + ow : 0;
    }

    float acc[4][8];
#pragma unroll
    for (int j = 0; j < 4; j++)
#pragma unroll
        for (int u = 0; u < 8; u++) acc[j][u] = 0.f;

#pragma unroll 1
    for (int ic = 0; ic < 3; ic++) {
        const int icb = ic * 1156;
#pragma unroll 1
        for (int kh = 0; kh < 5; kh++) {
#pragma unroll
            for (int kw = 0; kw < 5; kw++) {
                const float4* wr =
                    (const float4*)&w1t[(ic * 25 + kh * 5 + kw) * 96 + oc0];
                float4 w0 = wr[0], w1v = wr[1];
#pragma unroll
                for (int j = 0; j < 4; j++) {
                    float v = simg[icb + base[j] + kh * 34 + kw];
#pragma unroll
                    for (int u = 0; u < 4; u++) {
                        acc[j][u] = fmaf((&w0.x)[u], v, acc[j][u]);
                        acc[j][u + 4] = fmaf((&w1v.x)[u], v, acc[j][u + 4]);
                    }
                }
            }
        }
    }
#pragma unroll
    for (int j = 0; j < 4; j++)
        if (valid[j]) {
            int p = t + j * 256;
#pragma unroll
            for (int u = 0; u < 8; u++) c1s[u][p] = acc[j][u];
        }
    __syncthreads();
    if (t < 196) {
        const int ph = t / 14, pw = t % 14;
        ushort hv[8], lv[8];
#pragma unroll
        for (int u = 0; u < 8; u++) {
            float m = c1s[u][(2 * ph) * 30 + 2 * pw];
#pragma unroll
            for (int q = 1; q < 9; q++) {
                int dy = q / 3, dx = q % 3;
                m = fmaxf(m, c1s[u][(2 * ph + dy) * 30 + 2 * pw + dx]);
            }
            float o = fmaxf(m + b1[oc0 + u], 0.f);
            split_bf16(o, hv[u], lv[u]);
        }
        size_t ob = (((size_t)b * 18 + ph + 2) * 18 + pw + 2) * 96 + oc0;
        *(bf16x8*)&h1hi[ob] = *(bf16x8*)&hv[0];
        *(bf16x8*)&h1lo[ob] = *(bf16x8*)&lv[0];
    }
}

// ---------------- conv v6: A dbuf gld_lds, B reg->single LDS, raw barriers --
template <int BM, int IC, int H, int W, int OH, int OW, int OC, int NM>
__global__ __launch_bounds__(256, 3) void convmfma6_k(
        const ushort* __restrict__ ah, int aoff,
        const ushort* __restrict__ wh, int boff,
        const float* __restrict__ bias, float* __restrict__ C) {
    constexpr int K = 25 * IC;
    constexpr int MI = BM / 32;
    constexpr int G = NM * (OC / 128);
    __shared__ ushort At[2][BM * 64];
    __shared__ ushort Bt[128 * 64];
    const int t = threadIdx.x;
    const int lane = t & 63, wv = t >> 6;
    const int id = blockIdx.x;
    const int id2 = (id & 7) * (G >> 3) + (id >> 3);
    const int n0 = (id2 / NM) * 128;
    const int m0 = (id2 % NM) * BM;
    const int wm = (wv >> 1) * (BM / 2);
    const int wn = (wv & 1) * 64;

    const int srow = lane >> 3;
    const int slot = lane & 7;
    const int part = slot ^ srow;
    const bool hiA = part < 4;
    const int pk = (part & 3) * 8;

    int arb[MI];
#pragma unroll
    for (int rr = 0; rr < MI; rr++) {
        int r = wv * (BM / 4) + rr * 8 + srow;
        int m = m0 + r;
        int b = m / (OH * OW), pxy = m % (OH * OW);
        int oh = pxy / OW, ow = pxy % OW;
        arb[rr] = ((b * H + oh) * W + ow) * IC + pk;
    }
    const ushort* __restrict__ aptr = ah + (hiA ? 0 : aoff);
    size_t brb[4];
#pragma unroll
    for (int rr = 0; rr < 4; rr++) {
        int r = wv * 32 + rr * 8 + srow;
        brb[rr] = (size_t)(n0 + r) * K + pk;
    }
    const ushort* __restrict__ bptr = wh + (hiA ? 0 : boff);

    f32x4 acc[MI][4];
#pragma unroll
    for (int i = 0; i < MI; i++)
#pragma unroll
        for (int j = 0; j < 4; j++) acc[i][j] = (f32x4)(0.f);

    const int q = lane >> 4;
    const int fr = lane & 15;

    auto stageA = [&](int buf, int k0s) {
        const int tap = k0s / IC;
        const int koff = ((tap / 5) * W + (tap % 5)) * IC + (k0s - tap * IC);
#pragma unroll
        for (int rr = 0; rr < MI; rr++)
            gld_lds16(aptr + arb[rr] + koff,
                      &At[buf][(wv * (BM / 4) + rr * 8) * 64]);
    };

    // prologue: B(0) -> regs, A(0) -> At[0]; drain, sync
    bf16x8 bregs[4];
#pragma unroll
    for (int rr = 0; rr < 4; rr++)
        bregs[rr] = *(const bf16x8*)&bptr[brb[rr]];
    stageA(0, 0);
    asm volatile("s_waitcnt vmcnt(0)" ::: "memory");
    __builtin_amdgcn_s_barrier();

    int cur = 0;
#pragma unroll 1
    for (int k0 = 0; k0 < K; k0 += 32) {
        // 1: commit B slab k0 to LDS (placement identical to gld_lds map)
#pragma unroll
        for (int rr = 0; rr < 4; rr++)
            *(bf16x8*)&Bt[(wv * 32 + rr * 8 + srow) * 64 + slot * 8] = bregs[rr];
        // 2: issue A(k0+32) prefetch (lands by bar7's vmcnt(0))
        const int nxt = k0 + 32;
        if (nxt < K) stageA(cur ^ 1, nxt);
        // 3: Bt writes visible (lgkm only; vmcnt NOT drained)
        asm volatile("s_waitcnt lgkmcnt(0)" ::: "memory");
        __builtin_amdgcn_s_barrier();
        // 4: fragment reads
        bf16x8 afh[MI], afl[MI], bfh[4], bfl[4];
#pragma unroll
        for (int i = 0; i < MI; i++) {
            int row = wm + fr + i * 16;
            afh[i] = *(const bf16x8*)&At[cur][row * 64 + ((q ^ (row & 7)) << 3)];
            afl[i] = *(const bf16x8*)&At[cur][row * 64 + (((4 | q) ^ (row & 7)) << 3)];
        }
#pragma unroll
        for (int j = 0; j < 4; j++) {
            int row = wn + fr + j * 16;
            bfh[j] = *(const bf16x8*)&Bt[row * 64 + ((q ^ (row & 7)) << 3)];
            bfl[j] = *(const bf16x8*)&Bt[row * 64 + (((4 | q) ^ (row & 7)) << 3)];
        }
        // 5: prefetch B(k0+32) into regs (overlaps MFMA)
        if (nxt < K) {
#pragma unroll
            for (int rr = 0; rr < 4; rr++)
                bregs[rr] = *(const bf16x8*)&bptr[brb[rr] + nxt];
        }
        // 6: MFMA cluster
        __builtin_amdgcn_s_setprio(1);
#pragma unroll
        for (int i = 0; i < MI; i++)
#pragma unroll
            for (int j = 0; j < 4; j++) {
                acc[i][j] = __builtin_amdgcn_mfma_f32_16x16x32_bf16(
                    afh[i], bfh[j], acc[i][j], 0, 0, 0);
                acc[i][j] = __builtin_amdgcn_mfma_f32_16x16x32_bf16(
                    afh[i], bfl[j], acc[i][j], 0, 0, 0);
                acc[i][j] = __builtin_amdgcn_mfma_f32_16x16x32_bf16(
                    afl[i], bfh[j], acc[i][j], 0, 0, 0);
            }
        __builtin_amdgcn_s_setprio(0);
        // 7: A(next) + bregs landed; all waves aligned
        asm volatile("s_waitcnt vmcnt(0)" ::: "memory");
        __builtin_amdgcn_s_barrier();
        cur ^= 1;
    }

    const int crow0 = (lane >> 4) * 4;
    const int ccol = lane & 15;
#pragma unroll
    for (int i = 0; i < MI; i++) {
        int gm = m0 + wm + i * 16 + crow0;
#pragma unroll
        for (int j = 0; j < 4; j++) {
            int gn = n0 + wn + j * 16 + ccol;
            float bb = bias[gn];
#pragma unroll
            for (int r = 0; r < 4; r++)
                C[(size_t)(gm + r) * OC + gn] = acc[i][j][r] + bb;
        }
    }
}

// ---------------- pool2 ----------------
__global__ void pool2_k(const float* __restrict__ in, ushort* __restrict__ ohi,
                        ushort* __restrict__ olo) {
    int idx = blockIdx.x * 256 + threadIdx.x;
    if (idx >= 512 * 36 * 128) return;
    int c = idx & 127;
    int tmp = idx >> 7;
    int pw = tmp % 6;
    int tmp2 = tmp / 6;
    int ph = tmp2 % 6;
    int b = tmp2 / 6;
    size_t base = (((size_t)b * 14 + 2 * ph) * 14 + 2 * pw) * 128 + c;
    float m = -3.4e38f;
#pragma unroll
    for (int dy = 0; dy < 3; dy++)
#pragma unroll
        for (int dx = 0; dx < 3; dx++)
            m = fmaxf(m, in[base + (dy * 14 + dx) * 128]);
    float v = fmaxf(m, 0.f);
    ushort h, l;
    split_bf16(v, h, l);
    size_t o = (((size_t)b * 10 + ph + 2) * 10 + pw + 2) * 128 + c;
    ohi[o] = h;
    olo[o] = l;
}

// ---------------- pool3 ----------------
__global__ void pool3_k(const float* __restrict__ in, float* __restrict__ h3) {
    int idx = blockIdx.x * 256 + threadIdx.x;
    if (idx >= 512 * 4 * 256) return;
    int c = idx & 255;
    int pw = (idx >> 8) & 1;
    int ph = (idx >> 9) & 1;
    int b = idx >> 10;
    size_t base = (((size_t)b * 6 + 2 * ph) * 6 + 2 * pw) * 256 + c;
    float m = -3.4e38f;
#pragma unroll
    for (int dy = 0; dy < 3; dy++)
#pragma unroll
        for (int dx = 0; dx < 3; dx++)
            m = fmaxf(m, in[base + (dy * 6 + dx) * 256]);
    h3[(size_t)b * 1024 + c * 4 + ph * 2 + pw] = fmaxf(m, 0.f);
}

// ---------------- 6-product 3-term-split MFMA FC GEMM -----------------------
template <int BIAS, int RELUOUT, int DUAL>
__global__ __launch_bounds__(256, 2) void gemmfc_k(
        const float* __restrict__ A, const ushort* __restrict__ B3, int boff,
        const float* __restrict__ bias, float* __restrict__ C,
        float* __restrict__ C2, int K, int N) {
    __shared__ ushort Aa[32][40], Ab[32][40], Ac[32][40];
    __shared__ ushort Ba[64][40], Bb[64][40], Bc[64][40];
    const int t = threadIdx.x;
    const int n0 = blockIdx.x * 64;
    const int m0 = blockIdx.y * 32;
    const int lane = t & 63, wv = t >> 6;
    const int wm = (wv >> 1) * 16, wn = (wv & 1) * 32;
    const int fr = lane & 15, kp = (lane >> 4) * 8;

    f32x4 acc[2], acc2[DUAL ? 2 : 1];
#pragma unroll
    for (int j = 0; j < 2; j++) acc[j] = (f32x4)(0.f);
    if constexpr (DUAL) {
#pragma unroll
        for (int j = 0; j < 2; j++) acc2[j] = (f32x4)(0.f);
    }

    const int ar = t >> 2, ak = (t & 3) * 8;

    for (int k0 = 0; k0 < K; k0 += 32) {
        float4 a0, a1;
        if (t < 128) {
            a0 = *(const float4*)&A[(size_t)(m0 + ar) * K + k0 + ak];
            a1 = *(const float4*)&A[(size_t)(m0 + ar) * K + k0 + ak + 4];
        }
        size_t bidx = (size_t)(n0 + ar) * K + k0 + ak;
        bf16x8 b0 = *(const bf16x8*)&B3[bidx];
        bf16x8 b1 = *(const bf16x8*)&B3[bidx + boff];
        bf16x8 b2 = *(const bf16x8*)&B3[bidx + 2 * (size_t)boff];
        __syncthreads();
        if (t < 128) {
            ushort sa[8], sb[8], sc[8];
#pragma unroll
            for (int e = 0; e < 4; e++)
                split3_bf16((&a0.x)[e], sa[e], sb[e], sc[e]);
#pragma unroll
            for (int e = 0; e < 4; e++)
                split3_bf16((&a1.x)[e], sa[4 + e], sb[4 + e], sc[4 + e]);
            *(bf16x8*)&Aa[ar][ak] = *(bf16x8*)sa;
            *(bf16x8*)&Ab[ar][ak] = *(bf16x8*)sb;
            *(bf16x8*)&Ac[ar][ak] = *(bf16x8*)sc;
        }
        *(bf16x8*)&Ba[ar][ak] = b0;
        *(bf16x8*)&Bb[ar][ak] = b1;
        *(bf16x8*)&Bc[ar][ak] = b2;
        __syncthreads();

        bf16x8 fa = *(const bf16x8*)&Aa[wm + fr][kp];
        bf16x8 fb = *(const bf16x8*)&Ab[wm + fr][kp];
        bf16x8 fc = *(const bf16x8*)&Ac[wm + fr][kp];
#pragma unroll
        for (int j = 0; j < 2; j++) {
            int row = wn + j * 16 + fr;
            bf16x8 ga = *(const bf16x8*)&Ba[row][kp];
            bf16x8 gb = *(const bf16x8*)&Bb[row][kp];
            bf16x8 gc = *(const bf16x8*)&Bc[row][kp];
            acc[j] = __builtin_amdgcn_mfma_f32_16x16x32_bf16(fa, ga, acc[j], 0, 0, 0);
            acc[j] = __builtin_amdgcn_mfma_f32_16x16x32_bf16(fa, gb, acc[j], 0, 0, 0);
            acc[j] = __builtin_amdgcn_mfma_f32_16x16x32_bf16(fb, ga, acc[j], 0, 0, 0);
            acc[j] = __builtin_amdgcn_mfma_f32_16x16x32_bf16(fa, gc, acc[j], 0, 0, 0);
            acc[j] = __builtin_amdgcn_mfma_f32_16x16x32_bf16(fc, ga, acc[j], 0, 0, 0);
            acc[j] = __builtin_amdgcn_mfma_f32_16x16x32_bf16(fb, gb, acc[j], 0, 0, 0);
            if constexpr (DUAL) {
                bf16x8 msk = ga >> 15;
                bf16x8 ra = ga & ~msk;
                bf16x8 rb = gb & ~msk;
                bf16x8 rc = gc & ~msk;
                acc2[j] = __builtin_amdgcn_mfma_f32_16x16x32_bf16(fa, ra, acc2[j], 0, 0, 0);
                acc2[j] = __builtin_amdgcn_mfma_f32_16x16x32_bf16(fa, rb, acc2[j], 0, 0, 0);
                acc2[j] = __builtin_amdgcn_mfma_f32_16x16x32_bf16(fb, ra, acc2[j], 0, 0, 0);
                acc2[j] = __builtin_amdgcn_mfma_f32_16x16x32_bf16(fa, rc, acc2[j], 0, 0, 0);
                acc2[j] = __builtin_amdgcn_mfma_f32_16x16x32_bf16(fc, ra, acc2[j], 0, 0, 0);
                acc2[j] = __builtin_amdgcn_mfma_f32_16x16x32_bf16(fb, rb, acc2[j], 0, 0, 0);
            }
        }
    }

    const int gm0 = m0 + wm + (lane >> 4) * 4;
#pragma unroll
    for (int j = 0; j < 2; j++) {
        int gn = n0 + wn + j * 16 + fr;
        float bb = BIAS ? bias[gn] : 0.f;
#pragma unroll
        for (int r = 0; r < 4; r++) {
            float v = acc[j][r] + bb;
            if constexpr (RELUOUT) v = fmaxf(v, 0.f);
            C[(size_t)(gm0 + r) * N + gn] = v;
            if constexpr (DUAL) C2[(size_t)(gm0 + r) * N + gn] = acc2[j][r];
        }
    }
}

// ---------------- zlab ----------------
__global__ __launch_bounds__(256) void zlab_k(
        const float* __restrict__ h6eb, const float* __restrict__ w3,
        const int* __restrict__ label, float* __restrict__ zlab) {
    __shared__ float red[4];
    const int b = blockIdx.x, t = threadIdx.x;
    const int lab = label[b];
    const float4* hp = (const float4*)(h6eb + (size_t)b * 2048);
    const float4* wp = (const float4*)(w3 + (size_t)lab * 2048);
    float s = 0.f;
    for (int i = t; i < 512; i += 256) {
        float4 h = hp[i], w = wp[i];
        s += h.x * fmaxf(w.x, 0.f) + h.y * fmaxf(w.y, 0.f) +
             h.z * fmaxf(w.z, 0.f) + h.w * fmaxf(w.w, 0.f);
    }
#pragma unroll
    for (int off = 32; off > 0; off >>= 1) s += __shfl_down(s, off, 64);
    if ((t & 63) == 0) red[t >> 6] = s;
    __syncthreads();
    if (t == 0) zlab[b] = red[0] + red[1] + red[2] + red[3];
}

// ---------------- s2 elementwise ----------------
__global__ void s2_k(const float* __restrict__ h6eb, const float* __restrict__ z2,
                     const float* __restrict__ w3, const int* __restrict__ label,
                     const float* __restrict__ zlab, float* __restrict__ s2) {
    int idx = blockIdx.x * 256 + threadIdx.x;
    int b = idx >> 11, j = idx & 2047;
    float zl = zlab[b], zv = z2[idx];
    float v = 0.f;
    if (zl > 0.f && zv > 0.f) {
        float wp = fmaxf(w3[(size_t)label[b] * 2048 + j], 0.f);
        v = h6eb[idx] * wp / (zl * zv);
    }
    s2[idx] = v;
}

// ---------------- excitation dropout ----------------
__global__ void edrop_k(const float* __restrict__ h5, const float* __restrict__ t,
                        const float* __restrict__ noise, float* __restrict__ hed) {
    int idx = blockIdx.x * 256 + threadIdx.x;
    float pe = h5[idx] * t[idx];
    float num = 1023.5f * pe;
    float retain = 1.f - num / (num + 0.5f * (1.f - pe));
    float m = (noise[idx] < retain) ? 1.f : 0.f;
    hed[idx] = (retain > 0.f) ? h5[idx] * m / retain : 0.f;
}

// ---------------- final fc3 ----------------
__global__ void fc3_out_k(const float* __restrict__ h6, const float* __restrict__ w,
                          const float* __restrict__ bias, float* __restrict__ out) {
    int idx = blockIdx.x * 256 + threadIdx.x;
    if (idx >= 5120) return;
    int b = idx / 10, c = idx % 10;
    const float4* hp = (const float4*)(h6 + (size_t)b * 2048);
    const float4* wp = (const float4*)(w + (size_t)c * 2048);
    float s = 0.f;
    for (int i = 0; i < 512; i++) {
        float4 h = hp[i], ww = wp[i];
        s += h.x * ww.x + h.y * ww.y + h.z * ww.z + h.w * ww.w;
    }
    out[idx] = s + bias[c];
}

// ---------------------------------------------------------------------------
extern "C" void kernel_launch(void* const* d_in, const int* in_sizes, int n_in,
                              void* d_out, int out_size, void* d_ws, size_t ws_size,
                              hipStream_t stream) {
    const float* x       = (const float*)d_in[0];
    const float* noise   = (const float*)d_in[1];
    const float* conv1_w = (const float*)d_in[2];
    const float* conv1_b = (const float*)d_in[3];
    const float* conv2_w = (const float*)d_in[4];
    const float* conv2_b = (const float*)d_in[5];
    const float* conv3_w = (const float*)d_in[6];
    const float* conv3_b = (const float*)d_in[7];
    const float* fc1_w   = (const float*)d_in[8];
    const float* fc1_b   = (const float*)d_in[9];
    const float* fc2_w   = (const float*)d_in[10];
    const float* fc2_b   = (const float*)d_in[11];
    const float* fc3_w   = (const float*)d_in[12];
    const float* fc3_b   = (const float*)d_in[13];
    const int*   label   = (const int*)d_in[14];
    float* out = (float*)d_out;

    const size_t N_H1 = (size_t)512 * 18 * 18 * 96;
    const size_t N_C2 = (size_t)512 * 14 * 14 * 128;
    const size_t N_H2 = (size_t)512 * 10 * 10 * 128;
    const size_t N_H3 = (size_t)512 * 1024;

    float* ws = (float*)d_ws;
    ushort* h1hi = (ushort*)ws;
    ushort* h1lo = h1hi + N_H1;           // contiguous: aoff = N_H1
    float* c3 = ws;
    float* c2 = ws + N_H1;
    float* h5   = c2;
    float* h6eb = c2 + 1 * 1048576;
    float* z2   = c2 + 2 * 1048576;
    float* s2   = c2 + 3 * 1048576;
    float* tb   = c2 + 4 * 1048576;
    float* hed  = c2 + 5 * 1048576;
    float* h6   = c2 + 6 * 1048576;
    float* zlab = c2 + 7 * 1048576;
    ushort* h2hi = (ushort*)(ws + N_H1 + N_C2);
    ushort* h2lo = h2hi + N_H2;           // contiguous: aoff = N_H2
    float* h3  = ws + N_H1 + N_C2 + N_H2;
    float* w1t = h3 + N_H3;
    ushort* w2sh = (ushort*)(w1t + 7200);
    ushort* w2sl = w2sh + 307200;                  // boff = 307200
    ushort* w3sh = w2sl + 307200;
    ushort* w3sl = w3sh + 819200;                  // boff = 819200
    ushort* w23  = w3sl + 819200;                  // 3 x 4194304 (fc2 raw)
    ushort* w2rt = w23 + 3 * 4194304;              // 3 x 4194304 (fc2 reluT)
    ushort* w13  = w2rt + 3 * 4194304;             // 3 x 2097152 (fc1 raw)

    // weight prep
    transw_k<<<(75 * 96 + 255) / 256, 256, 0, stream>>>(conv1_w, w1t, 96, 75);
    splitw_k<<<(307200 + 255) / 256, 256, 0, stream>>>(conv2_w, w2sh, w2sl, 128, 96);
    splitw_k<<<(819200 + 255) / 256, 256, 0, stream>>>(conv3_w, w3sh, w3sl, 256, 128);
    splitw3_k<<<16384, 256, 0, stream>>>(fc2_w, w23, 4194304, 4194304);
    splitw3t_relu_k<<<1024, 256, 0, stream>>>(fc2_w, w2rt, 4194304);
    splitw3_k<<<8192, 256, 0, stream>>>(fc1_w, w13, 2097152, 2097152);

    // zero padded hi/lo buffers
    zero_k<<<2048, 256, 0, stream>>>((float4*)h1hi, (int)(N_H1 / 4));
    zero_k<<<2048, 256, 0, stream>>>((float4*)h2hi, (int)(N_H2 / 4));

    // conv stack
    conv1_v3<<<dim3(512, 12), 256, 0, stream>>>(x, w1t, conv1_b, h1hi, h1lo);
    // conv2: 784 blocks @ 3/CU (768 concurrent, tail 1.02)
    convmfma6_k<128, 96, 18, 18, 14, 14, 128, 784><<<784, 256, 0, stream>>>(
        h1hi, (int)N_H1, w2sh, 307200, conv2_b, c2);
    pool2_k<<<(512 * 36 * 128 + 255) / 256, 256, 0, stream>>>(c2, h2hi, h2lo);
    // conv3: 576 blocks @ 3/CU
    convmfma6_k<64, 128, 10, 10, 6, 6, 256, 288><<<576, 256, 0, stream>>>(
        h2hi, (int)N_H2, w3sh, 819200, conv3_b, c3);
    pool3_k<<<(512 * 4 * 256 + 255) / 256, 256, 0, stream>>>(c3, h3);

    // fc1: 6-product MFMA (K=1024)
    gemmfc_k<1, 1, 0><<<dim3(32, 16), 256, 0, stream>>>(
        h3, w13, 2097152, fc1_b, h5, nullptr, 1024, 2048);

    // dual: h6_eb = relu(h5 W2^T + b); z2 = h5 relu(W2)^T
    gemmfc_k<1, 1, 1><<<dim3(32, 16), 256, 0, stream>>>(
        h5, w23, 4194304, fc2_b, h6eb, z2, 2048, 2048);

    // EB collapse
    zlab_k<<<512, 256, 0, stream>>>(h6eb, fc3_w, label, zlab);
    s2_k<<<4096, 256, 0, stream>>>(h6eb, z2, fc3_w, label, zlab, s2);

    // t = s2 @ relu(W2)
    gemmfc_k<0, 0, 0><<<dim3(32, 16), 256, 0, stream>>>(
        s2, w2rt, 4194304, nullptr, tb, nullptr, 2048, 2048);

    // excitation dropout
    edrop_k<<<4096, 256, 0, stream>>>(h5, tb, noise, hed);

    // h6 = relu(h_ed W2^T + b)
    gemmfc_k<1, 1, 0><<<dim3(32, 16), 256, 0, stream>>>(
        hed, w23, 4194304, fc2_b, h6, nullptr, 2048, 2048);

    // out
    fc3_out_k<<<20, 256, 0, stream>>>(h6, fc3_w, fc3_b, out);
}

// Round 12
// 821.649 us; speedup vs baseline: 1.0409x; 1.0409x over previous
//
#include <hip/hip_runtime.h>
#include <hip/hip_bf16.h>

// ---------------------------------------------------------------------------
// CNN + EB dropout. r12:
//  - convs: r10/r8 exact (global_load_lds 2-phase dbuf, launch_bounds(256,2),
//    BM=128 conv2 / BM=64 conv3, XCD swizzle). r11's reg-staged B reverted
//    (VGPR-staged streaming loads thrash L1/L2: FETCH 62->490MB, 3x confirmed).
//  - fc1/dual/t/h6: 6-product 3-term-split MFMA GEMM; LDS row pad [40]->[44]
//    (22-bank stride -> distinct start banks, kills the 9.4M bank conflicts).
// ---------------------------------------------------------------------------

typedef __attribute__((ext_vector_type(8))) short bf16x8;
typedef __attribute__((ext_vector_type(4))) float f32x4;

__device__ __forceinline__ void split_bf16(float x, ushort& h, ushort& l) {
    __hip_bfloat16 bh = __float2bfloat16(x);
    float fh = __bfloat162float(bh);
    __hip_bfloat16 bl = __float2bfloat16(x - fh);
    h = *(ushort*)&bh;
    l = *(ushort*)&bl;
}

__device__ __forceinline__ void split3_bf16(float x, ushort& a, ushort& b,
                                            ushort& c) {
    __hip_bfloat16 ba = __float2bfloat16(x);
    float fa = __bfloat162float(ba);
    float r = x - fa;
    __hip_bfloat16 bb = __float2bfloat16(r);
    float fb = __bfloat162float(bb);
    __hip_bfloat16 bc = __float2bfloat16(r - fb);
    a = *(ushort*)&ba;
    b = *(ushort*)&bb;
    c = *(ushort*)&bc;
}

__device__ __forceinline__ void gld_lds16(const void* g, void* l) {
    __builtin_amdgcn_global_load_lds(
        (const __attribute__((address_space(1))) unsigned int*)g,
        (__attribute__((address_space(3))) unsigned int*)l, 16, 0, 0);
}

// ---------------- zero fill ----------------
__global__ void zero_k(float4* __restrict__ p, int n4) {
    int idx = blockIdx.x * 256 + threadIdx.x;
    int stride = gridDim.x * 256;
    float4 z = {0.f, 0.f, 0.f, 0.f};
    for (int i = idx; i < n4; i += stride) p[i] = z;
}

// ---------------- conv1 weight transpose ----------------
__global__ void transw_k(const float* __restrict__ in, float* __restrict__ out,
                         int OC, int K) {
    int idx = blockIdx.x * 256 + threadIdx.x;
    if (idx >= OC * K) return;
    int oc = idx / K, k = idx % K;
    out[k * OC + oc] = in[idx];
}

// ---------------- conv weight split: OIHW -> bf16 hi/lo [oc][tap*IC+ic] -----
__global__ void splitw_k(const float* __restrict__ in, ushort* __restrict__ hi,
                         ushort* __restrict__ lo, int OC, int IC) {
    int idx = blockIdx.x * 256 + threadIdx.x;
    if (idx >= OC * IC * 25) return;
    int oc = idx / (IC * 25);
    int r = idx % (IC * 25);
    int ic = r / 25, tap = r % 25;
    float v = in[idx];
    ushort h, l;
    split_bf16(v, h, l);
    size_t k = (size_t)oc * IC * 25 + tap * IC + ic;
    hi[k] = h;
    lo[k] = l;
}

// ---------------- raw 3-term split (same [out][in] layout) ------------------
__global__ void splitw3_k(const float* __restrict__ in, ushort* __restrict__ out,
                          int off, int total) {
    int idx = blockIdx.x * 256 + threadIdx.x;
    if (idx >= total) return;
    ushort a, b, c;
    split3_bf16(in[idx], a, b, c);
    out[idx] = a;
    out[idx + off] = b;
    out[idx + 2 * off] = c;
}

// ---------------- fc2 relu + transpose 3-term split -------------------------
__global__ __launch_bounds__(256) void splitw3t_relu_k(
        const float* __restrict__ in, ushort* __restrict__ out, int off) {
    __shared__ float tile[64][65];
    const int bx = blockIdx.x & 31, by = blockIdx.x >> 5;
    const int j = threadIdx.x & 63, i0 = threadIdx.x >> 6;
    for (int i = i0; i < 64; i += 4)
        tile[i][j] = in[(size_t)(by * 64 + i) * 2048 + bx * 64 + j];
    __syncthreads();
    for (int r = i0; r < 64; r += 4) {
        float x = fmaxf(tile[j][r], 0.f);
        ushort a, b, c;
        split3_bf16(x, a, b, c);
        size_t o = (size_t)(bx * 64 + r) * 2048 + by * 64 + j;
        out[o] = a;
        out[o + off] = b;
        out[o + 2 * off] = c;
    }
}

// ---------------- conv1: f32 VALU, fused pool, writes pre-split hi/lo -------
__global__ __launch_bounds__(256) void conv1_v3(
        const float* __restrict__ x, const float* __restrict__ w1t,
        const float* __restrict__ b1, ushort* __restrict__ h1hi,
        ushort* __restrict__ h1lo) {
    __shared__ float simg[3 * 34 * 34];
    __shared__ float c1s[8][904];
    const int b = blockIdx.x, oc0 = blockIdx.y * 8, t = threadIdx.x;

    for (int i = t; i < 3 * 34 * 34; i += 256) simg[i] = 0.f;
    __syncthreads();
    for (int i = t; i < 3072; i += 256) {
        int ic = i >> 10, r = (i >> 5) & 31, c = i & 31;
        simg[ic * 1156 + (r + 1) * 34 + (c + 1)] = x[(size_t)b * 3072 + i];
    }
    __syncthreads();

    int base[4];
    bool valid[4];
#pragma unroll
    for (int j = 0; j < 4; j++) {
        int p = t + j * 256;
        valid[j] = p < 900;
        int oh = p / 30, ow = p % 30;
        base[j] = valid[j] ? oh * 34 + ow : 0;
    }

    float acc[4][8];
#pragma unroll
    for (int j = 0; j < 4; j++)
#pragma unroll
        for (int u = 0; u < 8; u++) acc[j][u] = 0.f;

#pragma unroll 1
    for (int ic = 0; ic < 3; ic++) {
        const int icb = ic * 1156;
#pragma unroll 1
        for (int kh = 0; kh < 5; kh++) {
#pragma unroll
            for (int kw = 0; kw < 5; kw++) {
                const float4* wr =
                    (const float4*)&w1t[(ic * 25 + kh * 5 + kw) * 96 + oc0];
                float4 w0 = wr[0], w1v = wr[1];
#pragma unroll
                for (int j = 0; j < 4; j++) {
                    float v = simg[icb + base[j] + kh * 34 + kw];
#pragma unroll
                    for (int u = 0; u < 4; u++) {
                        acc[j][u] = fmaf((&w0.x)[u], v, acc[j][u]);
                        acc[j][u + 4] = fmaf((&w1v.x)[u], v, acc[j][u + 4]);
                    }
                }
            }
        }
    }
#pragma unroll
    for (int j = 0; j < 4; j++)
        if (valid[j]) {
            int p = t + j * 256;
#pragma unroll
            for (int u = 0; u < 8; u++) c1s[u][p] = acc[j][u];
        }
    __syncthreads();
    if (t < 196) {
        const int ph = t / 14, pw = t % 14;
        ushort hv[8], lv[8];
#pragma unroll
        for (int u = 0; u < 8; u++) {
            float m = c1s[u][(2 * ph) * 30 + 2 * pw];
#pragma unroll
            for (int q = 1; q < 9; q++) {
                int dy = q / 3, dx = q % 3;
                m = fmaxf(m, c1s[u][(2 * ph + dy) * 30 + 2 * pw + dx]);
            }
            float o = fmaxf(m + b1[oc0 + u], 0.f);
            split_bf16(o, hv[u], lv[u]);
        }
        size_t ob = (((size_t)b * 18 + ph + 2) * 18 + pw + 2) * 96 + oc0;
        *(bf16x8*)&h1hi[ob] = *(bf16x8*)&hv[0];
        *(bf16x8*)&h1lo[ob] = *(bf16x8*)&lv[0];
    }
}

// ---------------- split-bf16 MFMA implicit-GEMM conv (r8/r10 exact) ---------
template <int BM, int IC, int H, int W, int OH, int OW, int OC, int NM>
__global__ __launch_bounds__(256, 2) void convmfma5_k(
        const ushort* __restrict__ ah, int aoff,
        const ushort* __restrict__ wh, int boff,
        const float* __restrict__ bias, float* __restrict__ C) {
    constexpr int K = 25 * IC;
    constexpr int MI = BM / 32;
    constexpr int G = NM * (OC / 128);
    __shared__ ushort At[2][BM * 64];
    __shared__ ushort Bt[2][128 * 64];
    const int t = threadIdx.x;
    const int lane = t & 63, wv = t >> 6;
    const int id = blockIdx.x;
    const int id2 = (id & 7) * (G >> 3) + (id >> 3);
    const int n0 = (id2 / NM) * 128;
    const int m0 = (id2 % NM) * BM;
    const int wm = (wv >> 1) * (BM / 2);
    const int wn = (wv & 1) * 64;

    const int srow = lane >> 3;
    const int slot = lane & 7;
    const int part = slot ^ srow;
    const bool hiA = part < 4;
    const int pk = (part & 3) * 8;

    int arb[MI];
#pragma unroll
    for (int rr = 0; rr < MI; rr++) {
        int r = wv * (BM / 4) + rr * 8 + srow;
        int m = m0 + r;
        int b = m / (OH * OW), pxy = m % (OH * OW);
        int oh = pxy / OW, ow = pxy % OW;
        arb[rr] = ((b * H + oh) * W + ow) * IC + pk;
    }
    const ushort* __restrict__ aptr = ah + (hiA ? 0 : aoff);
    size_t brb[4];
#pragma unroll
    for (int rr = 0; rr < 4; rr++) {
        int r = wv * 32 + rr * 8 + srow;
        brb[rr] = (size_t)(n0 + r) * K + pk;
    }
    const ushort* __restrict__ bptr = wh + (hiA ? 0 : boff);

    f32x4 acc[MI][4];
#pragma unroll
    for (int i = 0; i < MI; i++)
#pragma unroll
        for (int j = 0; j < 4; j++) acc[i][j] = (f32x4)(0.f);

    const int q = lane >> 4;
    const int fr = lane & 15;

    auto stage = [&](int buf, int k0s) {
        const int tap = k0s / IC;
        const int koff = ((tap / 5) * W + (tap % 5)) * IC + (k0s - tap * IC);
#pragma unroll
        for (int rr = 0; rr < MI; rr++)
            gld_lds16(aptr + arb[rr] + koff,
                      &At[buf][(wv * (BM / 4) + rr * 8) * 64]);
#pragma unroll
        for (int rr = 0; rr < 4; rr++)
            gld_lds16(bptr + brb[rr] + k0s,
                      &Bt[buf][(wv * 32 + rr * 8) * 64]);
    };

    stage(0, 0);
    __syncthreads();

    int cur = 0;
#pragma unroll 1
    for (int k0 = 0; k0 < K; k0 += 32) {
        bf16x8 afh[MI], afl[MI], bfh[4], bfl[4];
#pragma unroll
        for (int i = 0; i < MI; i++) {
            int row = wm + fr + i * 16;
            afh[i] = *(const bf16x8*)&At[cur][row * 64 + ((q ^ (row & 7)) << 3)];
            afl[i] = *(const bf16x8*)&At[cur][row * 64 + (((4 | q) ^ (row & 7)) << 3)];
        }
#pragma unroll
        for (int j = 0; j < 4; j++) {
            int row = wn + fr + j * 16;
            bfh[j] = *(const bf16x8*)&Bt[cur][row * 64 + ((q ^ (row & 7)) << 3)];
            bfl[j] = *(const bf16x8*)&Bt[cur][row * 64 + (((4 | q) ^ (row & 7)) << 3)];
        }
        const int nxt = k0 + 32;
        if (nxt < K) stage(cur ^ 1, nxt);

#pragma unroll
        for (int i = 0; i < MI; i++)
#pragma unroll
            for (int j = 0; j < 4; j++) {
                acc[i][j] = __builtin_amdgcn_mfma_f32_16x16x32_bf16(
                    afh[i], bfh[j], acc[i][j], 0, 0, 0);
                acc[i][j] = __builtin_amdgcn_mfma_f32_16x16x32_bf16(
                    afh[i], bfl[j], acc[i][j], 0, 0, 0);
                acc[i][j] = __builtin_amdgcn_mfma_f32_16x16x32_bf16(
                    afl[i], bfh[j], acc[i][j], 0, 0, 0);
            }
        __syncthreads();
        cur ^= 1;
    }

    const int crow0 = (lane >> 4) * 4;
    const int ccol = lane & 15;
#pragma unroll
    for (int i = 0; i < MI; i++) {
        int gm = m0 + wm + i * 16 + crow0;
#pragma unroll
        for (int j = 0; j < 4; j++) {
            int gn = n0 + wn + j * 16 + ccol;
            float bb = bias[gn];
#pragma unroll
            for (int r = 0; r < 4; r++)
                C[(size_t)(gm + r) * OC + gn] = acc[i][j][r] + bb;
        }
    }
}

// ---------------- pool2 ----------------
__global__ void pool2_k(const float* __restrict__ in, ushort* __restrict__ ohi,
                        ushort* __restrict__ olo) {
    int idx = blockIdx.x * 256 + threadIdx.x;
    if (idx >= 512 * 36 * 128) return;
    int c = idx & 127;
    int tmp = idx >> 7;
    int pw = tmp % 6;
    int tmp2 = tmp / 6;
    int ph = tmp2 % 6;
    int b = tmp2 / 6;
    size_t base = (((size_t)b * 14 + 2 * ph) * 14 + 2 * pw) * 128 + c;
    float m = -3.4e38f;
#pragma unroll
    for (int dy = 0; dy < 3; dy++)
#pragma unroll
        for (int dx = 0; dx < 3; dx++)
            m = fmaxf(m, in[base + (dy * 14 + dx) * 128]);
    float v = fmaxf(m, 0.f);
    ushort h, l;
    split_bf16(v, h, l);
    size_t o = (((size_t)b * 10 + ph + 2) * 10 + pw + 2) * 128 + c;
    ohi[o] = h;
    olo[o] = l;
}

// ---------------- pool3 ----------------
__global__ void pool3_k(const float* __restrict__ in, float* __restrict__ h3) {
    int idx = blockIdx.x * 256 + threadIdx.x;
    if (idx >= 512 * 4 * 256) return;
    int c = idx & 255;
    int pw = (idx >> 8) & 1;
    int ph = (idx >> 9) & 1;
    int b = idx >> 10;
    size_t base = (((size_t)b * 6 + 2 * ph) * 6 + 2 * pw) * 256 + c;
    float m = -3.4e38f;
#pragma unroll
    for (int dy = 0; dy < 3; dy++)
#pragma unroll
        for (int dx = 0; dx < 3; dx++)
            m = fmaxf(m, in[base + (dy * 6 + dx) * 256]);
    h3[(size_t)b * 1024 + c * 4 + ph * 2 + pw] = fmaxf(m, 0.f);
}

// ---------------- 6-product 3-term-split MFMA FC GEMM (pad 44) --------------
template <int BIAS, int RELUOUT, int DUAL>
__global__ __launch_bounds__(256, 2) void gemmfc_k(
        const float* __restrict__ A, const ushort* __restrict__ B3, int boff,
        const float* __restrict__ bias, float* __restrict__ C,
        float* __restrict__ C2, int K, int N) {
    __shared__ ushort Aa[32][44], Ab[32][44], Ac[32][44];
    __shared__ ushort Ba[64][44], Bb[64][44], Bc[64][44];
    const int t = threadIdx.x;
    const int n0 = blockIdx.x * 64;
    const int m0 = blockIdx.y * 32;
    const int lane = t & 63, wv = t >> 6;
    const int wm = (wv >> 1) * 16, wn = (wv & 1) * 32;
    const int fr = lane & 15, kp = (lane >> 4) * 8;

    f32x4 acc[2], acc2[DUAL ? 2 : 1];
#pragma unroll
    for (int j = 0; j < 2; j++) acc[j] = (f32x4)(0.f);
    if constexpr (DUAL) {
#pragma unroll
        for (int j = 0; j < 2; j++) acc2[j] = (f32x4)(0.f);
    }

    const int ar = t >> 2, ak = (t & 3) * 8;

    for (int k0 = 0; k0 < K; k0 += 32) {
        float4 a0, a1;
        if (t < 128) {
            a0 = *(const float4*)&A[(size_t)(m0 + ar) * K + k0 + ak];
            a1 = *(const float4*)&A[(size_t)(m0 + ar) * K + k0 + ak + 4];
        }
        size_t bidx = (size_t)(n0 + ar) * K + k0 + ak;
        bf16x8 b0 = *(const bf16x8*)&B3[bidx];
        bf16x8 b1 = *(const bf16x8*)&B3[bidx + boff];
        bf16x8 b2 = *(const bf16x8*)&B3[bidx + 2 * (size_t)boff];
        __syncthreads();
        if (t < 128) {
            ushort sa[8], sb[8], sc[8];
#pragma unroll
            for (int e = 0; e < 4; e++)
                split3_bf16((&a0.x)[e], sa[e], sb[e], sc[e]);
#pragma unroll
            for (int e = 0; e < 4; e++)
                split3_bf16((&a1.x)[e], sa[4 + e], sb[4 + e], sc[4 + e]);
            *(bf16x8*)&Aa[ar][ak] = *(bf16x8*)sa;
            *(bf16x8*)&Ab[ar][ak] = *(bf16x8*)sb;
            *(bf16x8*)&Ac[ar][ak] = *(bf16x8*)sc;
        }
        *(bf16x8*)&Ba[ar][ak] = b0;
        *(bf16x8*)&Bb[ar][ak] = b1;
        *(bf16x8*)&Bc[ar][ak] = b2;
        __syncthreads();

        bf16x8 fa = *(const bf16x8*)&Aa[wm + fr][kp];
        bf16x8 fb = *(const bf16x8*)&Ab[wm + fr][kp];
        bf16x8 fc = *(const bf16x8*)&Ac[wm + fr][kp];
#pragma unroll
        for (int j = 0; j < 2; j++) {
            int row = wn + j * 16 + fr;
            bf16x8 ga = *(const bf16x8*)&Ba[row][kp];
            bf16x8 gb = *(const bf16x8*)&Bb[row][kp];
            bf16x8 gc = *(const bf16x8*)&Bc[row][kp];
            acc[j] = __builtin_amdgcn_mfma_f32_16x16x32_bf16(fa, ga, acc[j], 0, 0, 0);
            acc[j] = __builtin_amdgcn_mfma_f32_16x16x32_bf16(fa, gb, acc[j], 0, 0, 0);
            acc[j] = __builtin_amdgcn_mfma_f32_16x16x32_bf16(fb, ga, acc[j], 0, 0, 0);
            acc[j] = __builtin_amdgcn_mfma_f32_16x16x32_bf16(fa, gc, acc[j], 0, 0, 0);
            acc[j] = __builtin_amdgcn_mfma_f32_16x16x32_bf16(fc, ga, acc[j], 0, 0, 0);
            acc[j] = __builtin_amdgcn_mfma_f32_16x16x32_bf16(fb, gb, acc[j], 0, 0, 0);
            if constexpr (DUAL) {
                bf16x8 msk = ga >> 15;
                bf16x8 ra = ga & ~msk;
                bf16x8 rb = gb & ~msk;
                bf16x8 rc = gc & ~msk;
                acc2[j] = __builtin_amdgcn_mfma_f32_16x16x32_bf16(fa, ra, acc2[j], 0, 0, 0);
                acc2[j] = __builtin_amdgcn_mfma_f32_16x16x32_bf16(fa, rb, acc2[j], 0, 0, 0);
                acc2[j] = __builtin_amdgcn_mfma_f32_16x16x32_bf16(fb, ra, acc2[j], 0, 0, 0);
                acc2[j] = __builtin_amdgcn_mfma_f32_16x16x32_bf16(fa, rc, acc2[j], 0, 0, 0);
                acc2[j] = __builtin_amdgcn_mfma_f32_16x16x32_bf16(fc, ra, acc2[j], 0, 0, 0);
                acc2[j] = __builtin_amdgcn_mfma_f32_16x16x32_bf16(fb, rb, acc2[j], 0, 0, 0);
            }
        }
    }

    const int gm0 = m0 + wm + (lane >> 4) * 4;
#pragma unroll
    for (int j = 0; j < 2; j++) {
        int gn = n0 + wn + j * 16 + fr;
        float bb = BIAS ? bias[gn] : 0.f;
#pragma unroll
        for (int r = 0; r < 4; r++) {
            float v = acc[j][r] + bb;
            if constexpr (RELUOUT) v = fmaxf(v, 0.f);
            C[(size_t)(gm0 + r) * N + gn] = v;
            if constexpr (DUAL) C2[(size_t)(gm0 + r) * N + gn] = acc2[j][r];
        }
    }
}

// ---------------- zlab ----------------
__global__ __launch_bounds__(256) void zlab_k(
        const float* __restrict__ h6eb, const float* __restrict__ w3,
        const int* __restrict__ label, float* __restrict__ zlab) {
    __shared__ float red[4];
    const int b = blockIdx.x, t = threadIdx.x;
    const int lab = label[b];
    const float4* hp = (const float4*)(h6eb + (size_t)b * 2048);
    const float4* wp = (const float4*)(w3 + (size_t)lab * 2048);
    float s = 0.f;
    for (int i = t; i < 512; i += 256) {
        float4 h = hp[i], w = wp[i];
        s += h.x * fmaxf(w.x, 0.f) + h.y * fmaxf(w.y, 0.f) +
             h.z * fmaxf(w.z, 0.f) + h.w * fmaxf(w.w, 0.f);
    }
#pragma unroll
    for (int off = 32; off > 0; off >>= 1) s += __shfl_down(s, off, 64);
    if ((t & 63) == 0) red[t >> 6] = s;
    __syncthreads();
    if (t == 0) zlab[b] = red[0] + red[1] + red[2] + red[3];
}

// ---------------- s2 elementwise ----------------
__global__ void s2_k(const float* __restrict__ h6eb, const float* __restrict__ z2,
                     const float* __restrict__ w3, const int* __restrict__ label,
                     const float* __restrict__ zlab, float* __restrict__ s2) {
    int idx = blockIdx.x * 256 + threadIdx.x;
    int b = idx >> 11, j = idx & 2047;
    float zl = zlab[b], zv = z2[idx];
    float v = 0.f;
    if (zl > 0.f && zv > 0.f) {
        float wp = fmaxf(w3[(size_t)label[b] * 2048 + j], 0.f);
        v = h6eb[idx] * wp / (zl * zv);
    }
    s2[idx] = v;
}

// ---------------- excitation dropout ----------------
__global__ void edrop_k(const float* __restrict__ h5, const float* __restrict__ t,
                        const float* __restrict__ noise, float* __restrict__ hed) {
    int idx = blockIdx.x * 256 + threadIdx.x;
    float pe = h5[idx] * t[idx];
    float num = 1023.5f * pe;
    float retain = 1.f - num / (num + 0.5f * (1.f - pe));
    float m = (noise[idx] < retain) ? 1.f : 0.f;
    hed[idx] = (retain > 0.f) ? h5[idx] * m / retain : 0.f;
}

// ---------------- final fc3 ----------------
__global__ void fc3_out_k(const float* __restrict__ h6, const float* __restrict__ w,
                          const float* __restrict__ bias, float* __restrict__ out) {
    int idx = blockIdx.x * 256 + threadIdx.x;
    if (idx >= 5120) return;
    int b = idx / 10, c = idx % 10;
    const float4* hp = (const float4*)(h6 + (size_t)b * 2048);
    const float4* wp = (const float4*)(w + (size_t)c * 2048);
    float s = 0.f;
    for (int i = 0; i < 512; i++) {
        float4 h = hp[i], ww = wp[i];
        s += h.x * ww.x + h.y * ww.y + h.z * ww.z + h.w * ww.w;
    }
    out[idx] = s + bias[c];
}

// ---------------------------------------------------------------------------
extern "C" void kernel_launch(void* const* d_in, const int* in_sizes, int n_in,
                              void* d_out, int out_size, void* d_ws, size_t ws_size,
                              hipStream_t stream) {
    const float* x       = (const float*)d_in[0];
    const float* noise   = (const float*)d_in[1];
    const float* conv1_w = (const float*)d_in[2];
    const float* conv1_b = (const float*)d_in[3];
    const float* conv2_w = (const float*)d_in[4];
    const float* conv2_b = (const float*)d_in[5];
    const float* conv3_w = (const float*)d_in[6];
    const float* conv3_b = (const float*)d_in[7];
    const float* fc1_w   = (const float*)d_in[8];
    const float* fc1_b   = (const float*)d_in[9];
    const float* fc2_w   = (const float*)d_in[10];
    const float* fc2_b   = (const float*)d_in[11];
    const float* fc3_w   = (const float*)d_in[12];
    const float* fc3_b   = (const float*)d_in[13];
    const int*   label   = (const int*)d_in[14];
    float* out = (float*)d_out;

    const size_t N_H1 = (size_t)512 * 18 * 18 * 96;
    const size_t N_C2 = (size_t)512 * 14 * 14 * 128;
    const size_t N_H2 = (size_t)512 * 10 * 10 * 128;
    const size_t N_H3 = (size_t)512 * 1024;

    float* ws = (float*)d_ws;
    ushort* h1hi = (ushort*)ws;
    ushort* h1lo = h1hi + N_H1;           // contiguous: aoff = N_H1
    float* c3 = ws;
    float* c2 = ws + N_H1;
    float* h5   = c2;
    float* h6eb = c2 + 1 * 1048576;
    float* z2   = c2 + 2 * 1048576;
    float* s2   = c2 + 3 * 1048576;
    float* tb   = c2 + 4 * 1048576;
    float* hed  = c2 + 5 * 1048576;
    float* h6   = c2 + 6 * 1048576;
    float* zlab = c2 + 7 * 1048576;
    ushort* h2hi = (ushort*)(ws + N_H1 + N_C2);
    ushort* h2lo = h2hi + N_H2;           // contiguous: aoff = N_H2
    float* h3  = ws + N_H1 + N_C2 + N_H2;
    float* w1t = h3 + N_H3;
    ushort* w2sh = (ushort*)(w1t + 7200);
    ushort* w2sl = w2sh + 307200;                  // boff = 307200
    ushort* w3sh = w2sl + 307200;
    ushort* w3sl = w3sh + 819200;                  // boff = 819200
    ushort* w23  = w3sl + 819200;                  // 3 x 4194304 (fc2 raw)
    ushort* w2rt = w23 + 3 * 4194304;              // 3 x 4194304 (fc2 reluT)
    ushort* w13  = w2rt + 3 * 4194304;             // 3 x 2097152 (fc1 raw)

    // weight prep
    transw_k<<<(75 * 96 + 255) / 256, 256, 0, stream>>>(conv1_w, w1t, 96, 75);
    splitw_k<<<(307200 + 255) / 256, 256, 0, stream>>>(conv2_w, w2sh, w2sl, 128, 96);
    splitw_k<<<(819200 + 255) / 256, 256, 0, stream>>>(conv3_w, w3sh, w3sl, 256, 128);
    splitw3_k<<<16384, 256, 0, stream>>>(fc2_w, w23, 4194304, 4194304);
    splitw3t_relu_k<<<1024, 256, 0, stream>>>(fc2_w, w2rt, 4194304);
    splitw3_k<<<8192, 256, 0, stream>>>(fc1_w, w13, 2097152, 2097152);

    // zero padded hi/lo buffers
    zero_k<<<2048, 256, 0, stream>>>((float4*)h1hi, (int)(N_H1 / 4));
    zero_k<<<2048, 256, 0, stream>>>((float4*)h2hi, (int)(N_H2 / 4));

    // conv stack (r10 config)
    conv1_v3<<<dim3(512, 12), 256, 0, stream>>>(x, w1t, conv1_b, h1hi, h1lo);
    convmfma5_k<128, 96, 18, 18, 14, 14, 128, 784><<<784, 256, 0, stream>>>(
        h1hi, (int)N_H1, w2sh, 307200, conv2_b, c2);
    pool2_k<<<(512 * 36 * 128 + 255) / 256, 256, 0, stream>>>(c2, h2hi, h2lo);
    convmfma5_k<64, 128, 10, 10, 6, 6, 256, 288><<<576, 256, 0, stream>>>(
        h2hi, (int)N_H2, w3sh, 819200, conv3_b, c3);
    pool3_k<<<(512 * 4 * 256 + 255) / 256, 256, 0, stream>>>(c3, h3);

    // fc1: 6-product MFMA (K=1024)
    gemmfc_k<1, 1, 0><<<dim3(32, 16), 256, 0, stream>>>(
        h3, w13, 2097152, fc1_b, h5, nullptr, 1024, 2048);

    // dual: h6_eb = relu(h5 W2^T + b); z2 = h5 relu(W2)^T
    gemmfc_k<1, 1, 1><<<dim3(32, 16), 256, 0, stream>>>(
        h5, w23, 4194304, fc2_b, h6eb, z2, 2048, 2048);

    // EB collapse
    zlab_k<<<512, 256, 0, stream>>>(h6eb, fc3_w, label, zlab);
    s2_k<<<4096, 256, 0, stream>>>(h6eb, z2, fc3_w, label, zlab, s2);

    // t = s2 @ relu(W2)
    gemmfc_k<0, 0, 0><<<dim3(32, 16), 256, 0, stream>>>(
        s2, w2rt, 4194304, nullptr, tb, nullptr, 2048, 2048);

    // excitation dropout
    edrop_k<<<4096, 256, 0, stream>>>(h5, tb, noise, hed);

    // h6 = relu(h_ed W2^T + b)
    gemmfc_k<1, 1, 0><<<dim3(32, 16), 256, 0, stream>>>(
        hed, w23, 4194304, fc2_b, h6, nullptr, 2048, 2048);

    // out
    fc3_out_k<<<20, 256, 0, stream>>>(h6, fc3_w, fc3_b, out);
}

// Round 13
// 811.052 us; speedup vs baseline: 1.0545x; 1.0131x over previous
//
#include <hip/hip_runtime.h>
#include <hip/hip_bf16.h>

// ---------------------------------------------------------------------------
// CNN + EB dropout. r13:
//  - conv2: convmfma8: 512-thread blocks (8 waves, wave tile 32x64), r8's
//    1-barrier gld_lds double-buffer pipeline. 16 waves/CU (was 8).
//  - conv3: convmfma9: 256-thread, B single-buffered (LDS 32KB -> 3 blocks/CU,
//    all 576 blocks in ONE scheduling round), 2-barrier structure.
//  Both bit-identical in data placement + MFMA chains to r12.
//  - FC GEMMs: r12 (6-product 3-term split, pad 44) unchanged.
// ---------------------------------------------------------------------------

typedef __attribute__((ext_vector_type(8))) short bf16x8;
typedef __attribute__((ext_vector_type(4))) float f32x4;

__device__ __forceinline__ void split_bf16(float x, ushort& h, ushort& l) {
    __hip_bfloat16 bh = __float2bfloat16(x);
    float fh = __bfloat162float(bh);
    __hip_bfloat16 bl = __float2bfloat16(x - fh);
    h = *(ushort*)&bh;
    l = *(ushort*)&bl;
}

__device__ __forceinline__ void split3_bf16(float x, ushort& a, ushort& b,
                                            ushort& c) {
    __hip_bfloat16 ba = __float2bfloat16(x);
    float fa = __bfloat162float(ba);
    float r = x - fa;
    __hip_bfloat16 bb = __float2bfloat16(r);
    float fb = __bfloat162float(bb);
    __hip_bfloat16 bc = __float2bfloat16(r - fb);
    a = *(ushort*)&ba;
    b = *(ushort*)&bb;
    c = *(ushort*)&bc;
}

__device__ __forceinline__ void gld_lds16(const void* g, void* l) {
    __builtin_amdgcn_global_load_lds(
        (const __attribute__((address_space(1))) unsigned int*)g,
        (__attribute__((address_space(3))) unsigned int*)l, 16, 0, 0);
}

// ---------------- zero fill ----------------
__global__ void zero_k(float4* __restrict__ p, int n4) {
    int idx = blockIdx.x * 256 + threadIdx.x;
    int stride = gridDim.x * 256;
    float4 z = {0.f, 0.f, 0.f, 0.f};
    for (int i = idx; i < n4; i += stride) p[i] = z;
}

// ---------------- conv1 weight transpose ----------------
__global__ void transw_k(const float* __restrict__ in, float* __restrict__ out,
                         int OC, int K) {
    int idx = blockIdx.x * 256 + threadIdx.x;
    if (idx >= OC * K) return;
    int oc = idx / K, k = idx % K;
    out[k * OC + oc] = in[idx];
}

// ---------------- conv weight split: OIHW -> bf16 hi/lo [oc][tap*IC+ic] -----
__global__ void splitw_k(const float* __restrict__ in, ushort* __restrict__ hi,
                         ushort* __restrict__ lo, int OC, int IC) {
    int idx = blockIdx.x * 256 + threadIdx.x;
    if (idx >= OC * IC * 25) return;
    int oc = idx / (IC * 25);
    int r = idx % (IC * 25);
    int ic = r / 25, tap = r % 25;
    float v = in[idx];
    ushort h, l;
    split_bf16(v, h, l);
    size_t k = (size_t)oc * IC * 25 + tap * IC + ic;
    hi[k] = h;
    lo[k] = l;
}

// ---------------- raw 3-term split (same [out][in] layout) ------------------
__global__ void splitw3_k(const float* __restrict__ in, ushort* __restrict__ out,
                          int off, int total) {
    int idx = blockIdx.x * 256 + threadIdx.x;
    if (idx >= total) return;
    ushort a, b, c;
    split3_bf16(in[idx], a, b, c);
    out[idx] = a;
    out[idx + off] = b;
    out[idx + 2 * off] = c;
}

// ---------------- fc2 relu + transpose 3-term split -------------------------
__global__ __launch_bounds__(256) void splitw3t_relu_k(
        const float* __restrict__ in, ushort* __restrict__ out, int off) {
    __shared__ float tile[64][65];
    const int bx = blockIdx.x & 31, by = blockIdx.x >> 5;
    const int j = threadIdx.x & 63, i0 = threadIdx.x >> 6;
    for (int i = i0; i < 64; i += 4)
        tile[i][j] = in[(size_t)(by * 64 + i) * 2048 + bx * 64 + j];
    __syncthreads();
    for (int r = i0; r < 64; r += 4) {
        float x = fmaxf(tile[j][r], 0.f);
        ushort a, b, c;
        split3_bf16(x, a, b, c);
        size_t o = (size_t)(bx * 64 + r) * 2048 + by * 64 + j;
        out[o] = a;
        out[o + off] = b;
        out[o + 2 * off] = c;
    }
}

// ---------------- conv1: f32 VALU, fused pool, writes pre-split hi/lo -------
__global__ __launch_bounds__(256) void conv1_v3(
        const float* __restrict__ x, const float* __restrict__ w1t,
        const float* __restrict__ b1, ushort* __restrict__ h1hi,
        ushort* __restrict__ h1lo) {
    __shared__ float simg[3 * 34 * 34];
    __shared__ float c1s[8][904];
    const int b = blockIdx.x, oc0 = blockIdx.y * 8, t = threadIdx.x;

    for (int i = t; i < 3 * 34 * 34; i += 256) simg[i] = 0.f;
    __syncthreads();
    for (int i = t; i < 3072; i += 256) {
        int ic = i >> 10, r = (i >> 5) & 31, c = i & 31;
        simg[ic * 1156 + (r + 1) * 34 + (c + 1)] = x[(size_t)b * 3072 + i];
    }
    __syncthreads();

    int base[4];
    bool valid[4];
#pragma unroll
    for (int j = 0; j < 4; j++) {
        int p = t + j * 256;
        valid[j] = p < 900;
        int oh = p / 30, ow = p % 30;
        base[j] = valid[j] ? oh * 34 + ow : 0;
    }

    float acc[4][8];
#pragma unroll
    for (int j = 0; j < 4; j++)
#pragma unroll
        for (int u = 0; u < 8; u++) acc[j][u] = 0.f;

#pragma unroll 1
    for (int ic = 0; ic < 3; ic++) {
        const int icb = ic * 1156;
#pragma unroll 1
        for (int kh = 0; kh < 5; kh++) {
#pragma unroll
            for (int kw = 0; kw < 5; kw++) {
                const float4* wr =
                    (const float4*)&w1t[(ic * 25 + kh * 5 + kw) * 96 + oc0];
                float4 w0 = wr[0], w1v = wr[1];
#pragma unroll
                for (int j = 0; j < 4; j++) {
                    float v = simg[icb + base[j] + kh * 34 + kw];
#pragma unroll
                    for (int u = 0; u < 4; u++) {
                        acc[j][u] = fmaf((&w0.x)[u], v, acc[j][u]);
                        acc[j][u + 4] = fmaf((&w1v.x)[u], v, acc[j][u + 4]);
                    }
                }
            }
        }
    }
#pragma unroll
    for (int j = 0; j < 4; j++)
        if (valid[j]) {
            int p = t + j * 256;
#pragma unroll
            for (int u = 0; u < 8; u++) c1s[u][p] = acc[j][u];
        }
    __syncthreads();
    if (t < 196) {
        const int ph = t / 14, pw = t % 14;
        ushort hv[8], lv[8];
#pragma unroll
        for (int u = 0; u < 8; u++) {
            float m = c1s[u][(2 * ph) * 30 + 2 * pw];
#pragma unroll
            for (int q = 1; q < 9; q++) {
                int dy = q / 3, dx = q % 3;
                m = fmaxf(m, c1s[u][(2 * ph + dy) * 30 + 2 * pw + dx]);
            }
            float o = fmaxf(m + b1[oc0 + u], 0.f);
            split_bf16(o, hv[u], lv[u]);
        }
        size_t ob = (((size_t)b * 18 + ph + 2) * 18 + pw + 2) * 96 + oc0;
        *(bf16x8*)&h1hi[ob] = *(bf16x8*)&hv[0];
        *(bf16x8*)&h1lo[ob] = *(bf16x8*)&lv[0];
    }
}

// ---------------- conv2: 512-thread, 8 waves, wave tile 32x64 ---------------
// r8 1-barrier gld_lds dbuf pipeline; bit-identical data & MFMA chains.
template <int IC, int H, int W, int OH, int OW, int OC, int NM>
__global__ __launch_bounds__(512, 2) void convmfma8_k(
        const ushort* __restrict__ ah, int aoff,
        const ushort* __restrict__ wh, int boff,
        const float* __restrict__ bias, float* __restrict__ C) {
    constexpr int K = 25 * IC;
    constexpr int G = NM * (OC / 128);
    __shared__ ushort At[2][128 * 64];
    __shared__ ushort Bt[2][128 * 64];
    const int t = threadIdx.x;
    const int lane = t & 63, wv = t >> 6;   // 0..7
    const int id = blockIdx.x;
    const int id2 = (id & 7) * (G >> 3) + (id >> 3);
    const int n0 = (id2 / NM) * 128;
    const int m0 = (id2 % NM) * 128;
    const int wm = (wv >> 1) * 32;
    const int wn = (wv & 1) * 64;

    const int srow = lane >> 3;
    const int slot = lane & 7;
    const int part = slot ^ srow;
    const bool hiA = part < 4;
    const int pk = (part & 3) * 8;

    int arb[2];
#pragma unroll
    for (int rr = 0; rr < 2; rr++) {
        int r = wv * 16 + rr * 8 + srow;
        int m = m0 + r;
        int b = m / (OH * OW), pxy = m % (OH * OW);
        int oh = pxy / OW, ow = pxy % OW;
        arb[rr] = ((b * H + oh) * W + ow) * IC + pk;
    }
    const ushort* __restrict__ aptr = ah + (hiA ? 0 : aoff);
    size_t brb[2];
#pragma unroll
    for (int rr = 0; rr < 2; rr++) {
        int r = wv * 16 + rr * 8 + srow;
        brb[rr] = (size_t)(n0 + r) * K + pk;
    }
    const ushort* __restrict__ bptr = wh + (hiA ? 0 : boff);

    f32x4 acc[2][4];
#pragma unroll
    for (int i = 0; i < 2; i++)
#pragma unroll
        for (int j = 0; j < 4; j++) acc[i][j] = (f32x4)(0.f);

    const int q = lane >> 4;
    const int fr = lane & 15;

    auto stage = [&](int buf, int k0s) {
        const int tap = k0s / IC;
        const int koff = ((tap / 5) * W + (tap % 5)) * IC + (k0s - tap * IC);
#pragma unroll
        for (int rr = 0; rr < 2; rr++)
            gld_lds16(aptr + arb[rr] + koff, &At[buf][(wv * 16 + rr * 8) * 64]);
#pragma unroll
        for (int rr = 0; rr < 2; rr++)
            gld_lds16(bptr + brb[rr] + k0s, &Bt[buf][(wv * 16 + rr * 8) * 64]);
    };

    stage(0, 0);
    __syncthreads();

    int cur = 0;
#pragma unroll 1
    for (int k0 = 0; k0 < K; k0 += 32) {
        bf16x8 afh[2], afl[2], bfh[4], bfl[4];
#pragma unroll
        for (int i = 0; i < 2; i++) {
            int row = wm + fr + i * 16;
            afh[i] = *(const bf16x8*)&At[cur][row * 64 + ((q ^ (row & 7)) << 3)];
            afl[i] = *(const bf16x8*)&At[cur][row * 64 + (((4 | q) ^ (row & 7)) << 3)];
        }
#pragma unroll
        for (int j = 0; j < 4; j++) {
            int row = wn + fr + j * 16;
            bfh[j] = *(const bf16x8*)&Bt[cur][row * 64 + ((q ^ (row & 7)) << 3)];
            bfl[j] = *(const bf16x8*)&Bt[cur][row * 64 + (((4 | q) ^ (row & 7)) << 3)];
        }
        const int nxt = k0 + 32;
        if (nxt < K) stage(cur ^ 1, nxt);

#pragma unroll
        for (int i = 0; i < 2; i++)
#pragma unroll
            for (int j = 0; j < 4; j++) {
                acc[i][j] = __builtin_amdgcn_mfma_f32_16x16x32_bf16(
                    afh[i], bfh[j], acc[i][j], 0, 0, 0);
                acc[i][j] = __builtin_amdgcn_mfma_f32_16x16x32_bf16(
                    afh[i], bfl[j], acc[i][j], 0, 0, 0);
                acc[i][j] = __builtin_amdgcn_mfma_f32_16x16x32_bf16(
                    afl[i], bfh[j], acc[i][j], 0, 0, 0);
            }
        __syncthreads();
        cur ^= 1;
    }

    const int crow0 = (lane >> 4) * 4;
    const int ccol = lane & 15;
#pragma unroll
    for (int i = 0; i < 2; i++) {
        int gm = m0 + wm + i * 16 + crow0;
#pragma unroll
        for (int j = 0; j < 4; j++) {
            int gn = n0 + wn + j * 16 + ccol;
            float bb = bias[gn];
#pragma unroll
            for (int r = 0; r < 4; r++)
                C[(size_t)(gm + r) * OC + gn] = acc[i][j][r] + bb;
        }
    }
}

// ---------------- conv3: 256-thread, B single-buffer, 3 blocks/CU -----------
// 2-barrier pipeline: B-reads -> bar -> stage(A dbuf + B) -> A-reads || MFMA
// -> bar (vmcnt(0) drains stages). Bit-identical data & MFMA chains.
template <int IC, int H, int W, int OH, int OW, int OC, int NM>
__global__ __launch_bounds__(256, 3) void convmfma9_k(
        const ushort* __restrict__ ah, int aoff,
        const ushort* __restrict__ wh, int boff,
        const float* __restrict__ bias, float* __restrict__ C) {
    constexpr int K = 25 * IC;
    constexpr int G = NM * (OC / 128);
    __shared__ ushort At[2][64 * 64];
    __shared__ ushort Bt[128 * 64];
    const int t = threadIdx.x;
    const int lane = t & 63, wv = t >> 6;
    const int id = blockIdx.x;
    const int id2 = (id & 7) * (G >> 3) + (id >> 3);
    const int n0 = (id2 / NM) * 128;
    const int m0 = (id2 % NM) * 64;
    const int wm = (wv >> 1) * 32;
    const int wn = (wv & 1) * 64;

    const int srow = lane >> 3;
    const int slot = lane & 7;
    const int part = slot ^ srow;
    const bool hiA = part < 4;
    const int pk = (part & 3) * 8;

    int arb[2];
#pragma unroll
    for (int rr = 0; rr < 2; rr++) {
        int r = wv * 16 + rr * 8 + srow;
        int m = m0 + r;
        int b = m / (OH * OW), pxy = m % (OH * OW);
        int oh = pxy / OW, ow = pxy % OW;
        arb[rr] = ((b * H + oh) * W + ow) * IC + pk;
    }
    const ushort* __restrict__ aptr = ah + (hiA ? 0 : aoff);
    size_t brb[4];
#pragma unroll
    for (int rr = 0; rr < 4; rr++) {
        int r = wv * 32 + rr * 8 + srow;
        brb[rr] = (size_t)(n0 + r) * K + pk;
    }
    const ushort* __restrict__ bptr = wh + (hiA ? 0 : boff);

    f32x4 acc[2][4];
#pragma unroll
    for (int i = 0; i < 2; i++)
#pragma unroll
        for (int j = 0; j < 4; j++) acc[i][j] = (f32x4)(0.f);

    const int q = lane >> 4;
    const int fr = lane & 15;

    auto stageA = [&](int buf, int k0s) {
        const int tap = k0s / IC;
        const int koff = ((tap / 5) * W + (tap % 5)) * IC + (k0s - tap * IC);
#pragma unroll
        for (int rr = 0; rr < 2; rr++)
            gld_lds16(aptr + arb[rr] + koff, &At[buf][(wv * 16 + rr * 8) * 64]);
    };
    auto stageB = [&](int k0s) {
#pragma unroll
        for (int rr = 0; rr < 4; rr++)
            gld_lds16(bptr + brb[rr] + k0s, &Bt[(wv * 32 + rr * 8) * 64]);
    };

    stageA(0, 0);
    stageB(0);
    __syncthreads();

    int cur = 0;
#pragma unroll 1
    for (int k0 = 0; k0 < K; k0 += 32) {
        // B fragments first (Bt about to be overwritten)
        bf16x8 bfh[4], bfl[4];
#pragma unroll
        for (int j = 0; j < 4; j++) {
            int row = wn + fr + j * 16;
            bfh[j] = *(const bf16x8*)&Bt[row * 64 + ((q ^ (row & 7)) << 3)];
            bfl[j] = *(const bf16x8*)&Bt[row * 64 + (((4 | q) ^ (row & 7)) << 3)];
        }
        __syncthreads();   // all waves done reading Bt (lgkm drained)
        const int nxt = k0 + 32;
        if (nxt < K) {
            stageA(cur ^ 1, nxt);
            stageB(nxt);
        }
        bf16x8 afh[2], afl[2];
#pragma unroll
        for (int i = 0; i < 2; i++) {
            int row = wm + fr + i * 16;
            afh[i] = *(const bf16x8*)&At[cur][row * 64 + ((q ^ (row & 7)) << 3)];
            afl[i] = *(const bf16x8*)&At[cur][row * 64 + (((4 | q) ^ (row & 7)) << 3)];
        }
#pragma unroll
        for (int i = 0; i < 2; i++)
#pragma unroll
            for (int j = 0; j < 4; j++) {
                acc[i][j] = __builtin_amdgcn_mfma_f32_16x16x32_bf16(
                    afh[i], bfh[j], acc[i][j], 0, 0, 0);
                acc[i][j] = __builtin_amdgcn_mfma_f32_16x16x32_bf16(
                    afh[i], bfl[j], acc[i][j], 0, 0, 0);
                acc[i][j] = __builtin_amdgcn_mfma_f32_16x16x32_bf16(
                    afl[i], bfh[j], acc[i][j], 0, 0, 0);
            }
        __syncthreads();   // vmcnt(0): staged loads landed
        cur ^= 1;
    }

    const int crow0 = (lane >> 4) * 4;
    const int ccol = lane & 15;
#pragma unroll
    for (int i = 0; i < 2; i++) {
        int gm = m0 + wm + i * 16 + crow0;
#pragma unroll
        for (int j = 0; j < 4; j++) {
            int gn = n0 + wn + j * 16 + ccol;
            float bb = bias[gn];
#pragma unroll
            for (int r = 0; r < 4; r++)
                C[(size_t)(gm + r) * OC + gn] = acc[i][j][r] + bb;
        }
    }
}

// ---------------- pool2 ----------------
__global__ void pool2_k(const float* __restrict__ in, ushort* __restrict__ ohi,
                        ushort* __restrict__ olo) {
    int idx = blockIdx.x * 256 + threadIdx.x;
    if (idx >= 512 * 36 * 128) return;
    int c = idx & 127;
    int tmp = idx >> 7;
    int pw = tmp % 6;
    int tmp2 = tmp / 6;
    int ph = tmp2 % 6;
    int b = tmp2 / 6;
    size_t base = (((size_t)b * 14 + 2 * ph) * 14 + 2 * pw) * 128 + c;
    float m = -3.4e38f;
#pragma unroll
    for (int dy = 0; dy < 3; dy++)
#pragma unroll
        for (int dx = 0; dx < 3; dx++)
            m = fmaxf(m, in[base + (dy * 14 + dx) * 128]);
    float v = fmaxf(m, 0.f);
    ushort h, l;
    split_bf16(v, h, l);
    size_t o = (((size_t)b * 10 + ph + 2) * 10 + pw + 2) * 128 + c;
    ohi[o] = h;
    olo[o] = l;
}

// ---------------- pool3 ----------------
__global__ void pool3_k(const float* __restrict__ in, float* __restrict__ h3) {
    int idx = blockIdx.x * 256 + threadIdx.x;
    if (idx >= 512 * 4 * 256) return;
    int c = idx & 255;
    int pw = (idx >> 8) & 1;
    int ph = (idx >> 9) & 1;
    int b = idx >> 10;
    size_t base = (((size_t)b * 6 + 2 * ph) * 6 + 2 * pw) * 256 + c;
    float m = -3.4e38f;
#pragma unroll
    for (int dy = 0; dy < 3; dy++)
#pragma unroll
        for (int dx = 0; dx < 3; dx++)
            m = fmaxf(m, in[base + (dy * 6 + dx) * 256]);
    h3[(size_t)b * 1024 + c * 4 + ph * 2 + pw] = fmaxf(m, 0.f);
}

// ---------------- 6-product 3-term-split MFMA FC GEMM (pad 44) --------------
template <int BIAS, int RELUOUT, int DUAL>
__global__ __launch_bounds__(256, 2) void gemmfc_k(
        const float* __restrict__ A, const ushort* __restrict__ B3, int boff,
        const float* __restrict__ bias, float* __restrict__ C,
        float* __restrict__ C2, int K, int N) {
    __shared__ ushort Aa[32][44], Ab[32][44], Ac[32][44];
    __shared__ ushort Ba[64][44], Bb[64][44], Bc[64][44];
    const int t = threadIdx.x;
    const int n0 = blockIdx.x * 64;
    const int m0 = blockIdx.y * 32;
    const int lane = t & 63, wv = t >> 6;
    const int wm = (wv >> 1) * 16, wn = (wv & 1) * 32;
    const int fr = lane & 15, kp = (lane >> 4) * 8;

    f32x4 acc[2], acc2[DUAL ? 2 : 1];
#pragma unroll
    for (int j = 0; j < 2; j++) acc[j] = (f32x4)(0.f);
    if constexpr (DUAL) {
#pragma unroll
        for (int j = 0; j < 2; j++) acc2[j] = (f32x4)(0.f);
    }

    const int ar = t >> 2, ak = (t & 3) * 8;

    for (int k0 = 0; k0 < K; k0 += 32) {
        float4 a0, a1;
        if (t < 128) {
            a0 = *(const float4*)&A[(size_t)(m0 + ar) * K + k0 + ak];
            a1 = *(const float4*)&A[(size_t)(m0 + ar) * K + k0 + ak + 4];
        }
        size_t bidx = (size_t)(n0 + ar) * K + k0 + ak;
        bf16x8 b0 = *(const bf16x8*)&B3[bidx];
        bf16x8 b1 = *(const bf16x8*)&B3[bidx + boff];
        bf16x8 b2 = *(const bf16x8*)&B3[bidx + 2 * (size_t)boff];
        __syncthreads();
        if (t < 128) {
            ushort sa[8], sb[8], sc[8];
#pragma unroll
            for (int e = 0; e < 4; e++)
                split3_bf16((&a0.x)[e], sa[e], sb[e], sc[e]);
#pragma unroll
            for (int e = 0; e < 4; e++)
                split3_bf16((&a1.x)[e], sa[4 + e], sb[4 + e], sc[4 + e]);
            *(bf16x8*)&Aa[ar][ak] = *(bf16x8*)sa;
            *(bf16x8*)&Ab[ar][ak] = *(bf16x8*)sb;
            *(bf16x8*)&Ac[ar][ak] = *(bf16x8*)sc;
        }
        *(bf16x8*)&Ba[ar][ak] = b0;
        *(bf16x8*)&Bb[ar][ak] = b1;
        *(bf16x8*)&Bc[ar][ak] = b2;
        __syncthreads();

        bf16x8 fa = *(const bf16x8*)&Aa[wm + fr][kp];
        bf16x8 fb = *(const bf16x8*)&Ab[wm + fr][kp];
        bf16x8 fc = *(const bf16x8*)&Ac[wm + fr][kp];
#pragma unroll
        for (int j = 0; j < 2; j++) {
            int row = wn + j * 16 + fr;
            bf16x8 ga = *(const bf16x8*)&Ba[row][kp];
            bf16x8 gb = *(const bf16x8*)&Bb[row][kp];
            bf16x8 gc = *(const bf16x8*)&Bc[row][kp];
            acc[j] = __builtin_amdgcn_mfma_f32_16x16x32_bf16(fa, ga, acc[j], 0, 0, 0);
            acc[j] = __builtin_amdgcn_mfma_f32_16x16x32_bf16(fa, gb, acc[j], 0, 0, 0);
            acc[j] = __builtin_amdgcn_mfma_f32_16x16x32_bf16(fb, ga, acc[j], 0, 0, 0);
            acc[j] = __builtin_amdgcn_mfma_f32_16x16x32_bf16(fa, gc, acc[j], 0, 0, 0);
            acc[j] = __builtin_amdgcn_mfma_f32_16x16x32_bf16(fc, ga, acc[j], 0, 0, 0);
            acc[j] = __builtin_amdgcn_mfma_f32_16x16x32_bf16(fb, gb, acc[j], 0, 0, 0);
            if constexpr (DUAL) {
                bf16x8 msk = ga >> 15;
                bf16x8 ra = ga & ~msk;
                bf16x8 rb = gb & ~msk;
                bf16x8 rc = gc & ~msk;
                acc2[j] = __builtin_amdgcn_mfma_f32_16x16x32_bf16(fa, ra, acc2[j], 0, 0, 0);
                acc2[j] = __builtin_amdgcn_mfma_f32_16x16x32_bf16(fa, rb, acc2[j], 0, 0, 0);
                acc2[j] = __builtin_amdgcn_mfma_f32_16x16x32_bf16(fb, ra, acc2[j], 0, 0, 0);
                acc2[j] = __builtin_amdgcn_mfma_f32_16x16x32_bf16(fa, rc, acc2[j], 0, 0, 0);
                acc2[j] = __builtin_amdgcn_mfma_f32_16x16x32_bf16(fc, ra, acc2[j], 0, 0, 0);
                acc2[j] = __builtin_amdgcn_mfma_f32_16x16x32_bf16(fb, rb, acc2[j], 0, 0, 0);
            }
        }
    }

    const int gm0 = m0 + wm + (lane >> 4) * 4;
#pragma unroll
    for (int j = 0; j < 2; j++) {
        int gn = n0 + wn + j * 16 + fr;
        float bb = BIAS ? bias[gn] : 0.f;
#pragma unroll
        for (int r = 0; r < 4; r++) {
            float v = acc[j][r] + bb;
            if constexpr (RELUOUT) v = fmaxf(v, 0.f);
            C[(size_t)(gm0 + r) * N + gn] = v;
            if constexpr (DUAL) C2[(size_t)(gm0 + r) * N + gn] = acc2[j][r];
        }
    }
}

// ---------------- zlab ----------------
__global__ __launch_bounds__(256) void zlab_k(
        const float* __restrict__ h6eb, const float* __restrict__ w3,
        const int* __restrict__ label, float* __restrict__ zlab) {
    __shared__ float red[4];
    const int b = blockIdx.x, t = threadIdx.x;
    const int lab = label[b];
    const float4* hp = (const float4*)(h6eb + (size_t)b * 2048);
    const float4* wp = (const float4*)(w3 + (size_t)lab * 2048);
    float s = 0.f;
    for (int i = t; i < 512; i += 256) {
        float4 h = hp[i], w = wp[i];
        s += h.x * fmaxf(w.x, 0.f) + h.y * fmaxf(w.y, 0.f) +
             h.z * fmaxf(w.z, 0.f) + h.w * fmaxf(w.w, 0.f);
    }
#pragma unroll
    for (int off = 32; off > 0; off >>= 1) s += __shfl_down(s, off, 64);
    if ((t & 63) == 0) red[t >> 6] = s;
    __syncthreads();
    if (t == 0) zlab[b] = red[0] + red[1] + red[2] + red[3];
}

// ---------------- s2 elementwise ----------------
__global__ void s2_k(const float* __restrict__ h6eb, const float* __restrict__ z2,
                     const float* __restrict__ w3, const int* __restrict__ label,
                     const float* __restrict__ zlab, float* __restrict__ s2) {
    int idx = blockIdx.x * 256 + threadIdx.x;
    int b = idx >> 11, j = idx & 2047;
    float zl = zlab[b], zv = z2[idx];
    float v = 0.f;
    if (zl > 0.f && zv > 0.f) {
        float wp = fmaxf(w3[(size_t)label[b] * 2048 + j], 0.f);
        v = h6eb[idx] * wp / (zl * zv);
    }
    s2[idx] = v;
}

// ---------------- excitation dropout ----------------
__global__ void edrop_k(const float* __restrict__ h5, const float* __restrict__ t,
                        const float* __restrict__ noise, float* __restrict__ hed) {
    int idx = blockIdx.x * 256 + threadIdx.x;
    float pe = h5[idx] * t[idx];
    float num = 1023.5f * pe;
    float retain = 1.f - num / (num + 0.5f * (1.f - pe));
    float m = (noise[idx] < retain) ? 1.f : 0.f;
    hed[idx] = (retain > 0.f) ? h5[idx] * m / retain : 0.f;
}

// ---------------- final fc3 ----------------
__global__ void fc3_out_k(const float* __restrict__ h6, const float* __restrict__ w,
                          const float* __restrict__ bias, float* __restrict__ out) {
    int idx = blockIdx.x * 256 + threadIdx.x;
    if (idx >= 5120) return;
    int b = idx / 10, c = idx % 10;
    const float4* hp = (const float4*)(h6 + (size_t)b * 2048);
    const float4* wp = (const float4*)(w + (size_t)c * 2048);
    float s = 0.f;
    for (int i = 0; i < 512; i++) {
        float4 h = hp[i], ww = wp[i];
        s += h.x * ww.x + h.y * ww.y + h.z * ww.z + h.w * ww.w;
    }
    out[idx] = s + bias[c];
}

// ---------------------------------------------------------------------------
extern "C" void kernel_launch(void* const* d_in, const int* in_sizes, int n_in,
                              void* d_out, int out_size, void* d_ws, size_t ws_size,
                              hipStream_t stream) {
    const float* x       = (const float*)d_in[0];
    const float* noise   = (const float*)d_in[1];
    const float* conv1_w = (const float*)d_in[2];
    const float* conv1_b = (const float*)d_in[3];
    const float* conv2_w = (const float*)d_in[4];
    const float* conv2_b = (const float*)d_in[5];
    const float* conv3_w = (const float*)d_in[6];
    const float* conv3_b = (const float*)d_in[7];
    const float* fc1_w   = (const float*)d_in[8];
    const float* fc1_b   = (const float*)d_in[9];
    const float* fc2_w   = (const float*)d_in[10];
    const float* fc2_b   = (const float*)d_in[11];
    const float* fc3_w   = (const float*)d_in[12];
    const float* fc3_b   = (const float*)d_in[13];
    const int*   label   = (const int*)d_in[14];
    float* out = (float*)d_out;

    const size_t N_H1 = (size_t)512 * 18 * 18 * 96;
    const size_t N_C2 = (size_t)512 * 14 * 14 * 128;
    const size_t N_H2 = (size_t)512 * 10 * 10 * 128;
    const size_t N_H3 = (size_t)512 * 1024;

    float* ws = (float*)d_ws;
    ushort* h1hi = (ushort*)ws;
    ushort* h1lo = h1hi + N_H1;           // contiguous: aoff = N_H1
    float* c3 = ws;
    float* c2 = ws + N_H1;
    float* h5   = c2;
    float* h6eb = c2 + 1 * 1048576;
    float* z2   = c2 + 2 * 1048576;
    float* s2   = c2 + 3 * 1048576;
    float* tb   = c2 + 4 * 1048576;
    float* hed  = c2 + 5 * 1048576;
    float* h6   = c2 + 6 * 1048576;
    float* zlab = c2 + 7 * 1048576;
    ushort* h2hi = (ushort*)(ws + N_H1 + N_C2);
    ushort* h2lo = h2hi + N_H2;           // contiguous: aoff = N_H2
    float* h3  = ws + N_H1 + N_C2 + N_H2;
    float* w1t = h3 + N_H3;
    ushort* w2sh = (ushort*)(w1t + 7200);
    ushort* w2sl = w2sh + 307200;                  // boff = 307200
    ushort* w3sh = w2sl + 307200;
    ushort* w3sl = w3sh + 819200;                  // boff = 819200
    ushort* w23  = w3sl + 819200;                  // 3 x 4194304 (fc2 raw)
    ushort* w2rt = w23 + 3 * 4194304;              // 3 x 4194304 (fc2 reluT)
    ushort* w13  = w2rt + 3 * 4194304;             // 3 x 2097152 (fc1 raw)

    // weight prep
    transw_k<<<(75 * 96 + 255) / 256, 256, 0, stream>>>(conv1_w, w1t, 96, 75);
    splitw_k<<<(307200 + 255) / 256, 256, 0, stream>>>(conv2_w, w2sh, w2sl, 128, 96);
    splitw_k<<<(819200 + 255) / 256, 256, 0, stream>>>(conv3_w, w3sh, w3sl, 256, 128);
    splitw3_k<<<16384, 256, 0, stream>>>(fc2_w, w23, 4194304, 4194304);
    splitw3t_relu_k<<<1024, 256, 0, stream>>>(fc2_w, w2rt, 4194304);
    splitw3_k<<<8192, 256, 0, stream>>>(fc1_w, w13, 2097152, 2097152);

    // zero padded hi/lo buffers
    zero_k<<<2048, 256, 0, stream>>>((float4*)h1hi, (int)(N_H1 / 4));
    zero_k<<<2048, 256, 0, stream>>>((float4*)h2hi, (int)(N_H2 / 4));

    // conv stack
    conv1_v3<<<dim3(512, 12), 256, 0, stream>>>(x, w1t, conv1_b, h1hi, h1lo);
    // conv2: 784 blocks x 512 threads (16 waves/CU)
    convmfma8_k<96, 18, 18, 14, 14, 128, 784><<<784, 512, 0, stream>>>(
        h1hi, (int)N_H1, w2sh, 307200, conv2_b, c2);
    pool2_k<<<(512 * 36 * 128 + 255) / 256, 256, 0, stream>>>(c2, h2hi, h2lo);
    // conv3: 576 blocks @ 3/CU -> one scheduling round
    convmfma9_k<128, 10, 10, 6, 6, 256, 288><<<576, 256, 0, stream>>>(
        h2hi, (int)N_H2, w3sh, 819200, conv3_b, c3);
    pool3_k<<<(512 * 4 * 256 + 255) / 256, 256, 0, stream>>>(c3, h3);

    // fc1: 6-product MFMA (K=1024)
    gemmfc_k<1, 1, 0><<<dim3(32, 16), 256, 0, stream>>>(
        h3, w13, 2097152, fc1_b, h5, nullptr, 1024, 2048);

    // dual: h6_eb = relu(h5 W2^T + b); z2 = h5 relu(W2)^T
    gemmfc_k<1, 1, 1><<<dim3(32, 16), 256, 0, stream>>>(
        h5, w23, 4194304, fc2_b, h6eb, z2, 2048, 2048);

    // EB collapse
    zlab_k<<<512, 256, 0, stream>>>(h6eb, fc3_w, label, zlab);
    s2_k<<<4096, 256, 0, stream>>>(h6eb, z2, fc3_w, label, zlab, s2);

    // t = s2 @ relu(W2)
    gemmfc_k<0, 0, 0><<<dim3(32, 16), 256, 0, stream>>>(
        s2, w2rt, 4194304, nullptr, tb, nullptr, 2048, 2048);

    // excitation dropout
    edrop_k<<<4096, 256, 0, stream>>>(h5, tb, noise, hed);

    // h6 = relu(h_ed W2^T + b)
    gemmfc_k<1, 1, 0><<<dim3(32, 16), 256, 0, stream>>>(
        hed, w23, 4194304, fc2_b, h6, nullptr, 2048, 2048);

    // out
    fc3_out_k<<<20, 256, 0, stream>>>(h6, fc3_w, fc3_b, out);
}